// Round 13
// baseline (244.943 us; speedup 1.0000x reference)
//
#include <hip/hip_runtime.h>

#define D 128
#define NB 250    // node buckets
#define BN 200    // nodes per bucket (NB*BN == n == 50000)
#define NBLK 512  // histogram/partition blocks (power of 2)
#define CAP 7168  // LDS-staged edges per bucket; global-read fallback past this
#define PADB 600  // worst-case per-bucket padding (BN * 3)

typedef float f2v __attribute__((ext_vector_type(2)));
typedef short bf16x8 __attribute__((ext_vector_type(8)));
typedef float f32x4 __attribute__((ext_vector_type(4)));

// bf16 round-to-nearest-even
__device__ __forceinline__ unsigned bf16r(float f) {
  unsigned u = __float_as_uint(f);
  return (u + 0x7fffu + ((u >> 16) & 1u)) >> 16;
}

// ---------------- pass A + converts ----------------
// blocks [0,NBLK): LDS bucket histogram of dst -> M[bkt][blk] (transposed)
// blocks [NBLK,NBLK+GC): x -> bf16 ; rest: W -> bf16 transposed [n][k]

__global__ __launch_bounds__(256) void k_pre1(const int* __restrict__ dst, int* __restrict__ M, int E,
                                              const float* __restrict__ X, unsigned short* __restrict__ Xb,
                                              int total4, int GC,
                                              const float* __restrict__ W0, const float* __restrict__ W1,
                                              const float* __restrict__ W2, unsigned short* __restrict__ Wt) {
  __shared__ int lh[NB];
  int b = blockIdx.x;
  int tid = threadIdx.x;
  if (b < NBLK) {
    for (int i = tid; i < NB; i += 256) lh[i] = 0;
    __syncthreads();
    const int EPB = (E + NBLK - 1) / NBLK;
    int e0 = b * EPB;
    int e1 = min(e0 + EPB, E);
    for (int e = e0 + tid; e < e1; e += 256) atomicAdd(&lh[dst[e] / BN], 1);
    __syncthreads();
    for (int i = tid; i < NB; i += 256) M[i * NBLK + b] = lh[i];
  } else if (b < NBLK + GC) {
    int i = (b - NBLK) * 256 + tid;
    if (i < total4) {
      float4 v = ((const float4*)X)[i];
      ushort4 o;
      o.x = (unsigned short)bf16r(v.x);
      o.y = (unsigned short)bf16r(v.y);
      o.z = (unsigned short)bf16r(v.z);
      o.w = (unsigned short)bf16r(v.w);
      ((ushort4*)Xb)[i] = o;
    }
  } else {
    int i = (b - NBLK - GC) * 256 + tid;
    if (i < 3 * 16384) {
      int l = i >> 14;
      int r = i & 16383;
      int nn = r >> 7, kk = r & 127;
      const float* W = (l == 0) ? W0 : (l == 1) ? W1 : W2;
      Wt[i] = (unsigned short)bf16r(W[kk * 128 + nn]);
    }
  }
}

// ---------------- hierarchical scan of M (flat, bucket-major) ----------------

__global__ __launch_bounds__(256) void k_blocksum(const int* __restrict__ cnt, int* __restrict__ bsum, int n) {
  int i = blockIdx.x * 256 + threadIdx.x;
  int v = (i < n) ? cnt[i] : 0;
#pragma unroll
  for (int off = 32; off > 0; off >>= 1) v += __shfl_down(v, off);
  __shared__ int ws[4];
  if ((threadIdx.x & 63) == 0) ws[threadIdx.x >> 6] = v;
  __syncthreads();
  if (threadIdx.x == 0) bsum[blockIdx.x] = ws[0] + ws[1] + ws[2] + ws[3];
}

__global__ __launch_bounds__(512) void k_scanb2(const int* __restrict__ bsum, int* __restrict__ boff, int nb) {
  __shared__ int s[512];
  int t = threadIdx.x;
  int v = (t < nb) ? bsum[t] : 0;
  s[t] = v;
  __syncthreads();
#pragma unroll
  for (int off = 1; off < 512; off <<= 1) {
    int u = (t >= off) ? s[t - off] : 0;
    __syncthreads();
    s[t] += u;
    __syncthreads();
  }
  if (t < nb) boff[t] = s[t] - v;  // exclusive
}

__global__ __launch_bounds__(256) void k_scanm(int* __restrict__ M, const int* __restrict__ boff,
                                               int* __restrict__ bbase, int flatN, int Etot) {
  __shared__ int s[256];
  int t = threadIdx.x;
  int i = blockIdx.x * 256 + t;
  int v = (i < flatN) ? M[i] : 0;
  s[t] = v;
  __syncthreads();
#pragma unroll
  for (int off = 1; off < 256; off <<= 1) {
    int u = (t >= off) ? s[t - off] : 0;
    __syncthreads();
    s[t] += u;
    __syncthreads();
  }
  int ex = s[t] - v + boff[blockIdx.x];
  if (i < flatN) {
    M[i] = ex;
    if ((i & (NBLK - 1)) == 0) bbase[i / NBLK] = ex;
  }
  if (i == 0) bbase[NB] = Etot;
}

// ---------------- pass B + layer-0 GEMM ----------------

__global__ __launch_bounds__(256) void k_pre2(const unsigned short* __restrict__ Zb,
                                              const unsigned short* __restrict__ Wt,
                                              unsigned short* __restrict__ H, int n, int GG,
                                              const int* __restrict__ src, const int* __restrict__ dst,
                                              const float* __restrict__ ew, const int* __restrict__ M,
                                              uint2* __restrict__ part, int E) {
  __shared__ int lcur[NB];
  int b = blockIdx.x;
  if (b < GG) {
    int lane = threadIdx.x & 63;
    int wid  = threadIdx.x >> 6;
    int row0 = b * 16;
    int r  = lane & 15;
    int kg = lane >> 4;
    int c0 = wid * 32;
    const size_t abase  = (size_t)(row0 + r) * 128 + kg * 8;
    const size_t b0base = (size_t)(c0 + r) * 128 + kg * 8;
    const size_t b1base = (size_t)(c0 + 16 + r) * 128 + kg * 8;
    f32x4 acc0 = {0.f, 0.f, 0.f, 0.f};
    f32x4 acc1 = {0.f, 0.f, 0.f, 0.f};
#pragma unroll
    for (int k0 = 0; k0 < 128; k0 += 32) {
      bf16x8 a  = *(const bf16x8*)&Zb[abase + k0];
      bf16x8 b0 = *(const bf16x8*)&Wt[b0base + k0];
      bf16x8 b1 = *(const bf16x8*)&Wt[b1base + k0];
      acc0 = __builtin_amdgcn_mfma_f32_16x16x32_bf16(a, b0, acc0, 0, 0, 0);
      acc1 = __builtin_amdgcn_mfma_f32_16x16x32_bf16(a, b1, acc1, 0, 0, 0);
    }
    int orow = row0 + kg * 4;
#pragma unroll
    for (int j = 0; j < 4; ++j) {
      H[(size_t)(orow + j) * 128 + c0 + r]      = (unsigned short)bf16r(acc0[j]);
      H[(size_t)(orow + j) * 128 + c0 + 16 + r] = (unsigned short)bf16r(acc1[j]);
    }
  } else {
    int blk = b - GG;
    int tid = threadIdx.x;
    for (int i = tid; i < NB; i += 256) lcur[i] = M[i * NBLK + blk];
    __syncthreads();
    const int EPB = (E + NBLK - 1) / NBLK;
    int e0 = blk * EPB;
    int e1 = min(e0 + EPB, E);
    for (int e = e0 + tid; e < e1; e += 256) {
      int d = dst[e];
      int bkt = d / BN;
      int dlow = d - bkt * BN;
      int p = atomicAdd(&lcur[bkt], 1);
      uint2 rec;
      rec.x = (unsigned)src[e] | ((unsigned)dlow << 24);
      rec.y = __float_as_uint(ew[e]);
      part[p] = rec;
    }
  }
}

// ---------------- pass C1: per-bucket degree -> dis ----------------

__global__ __launch_bounds__(256) void k_deg(const uint2* __restrict__ part, const int* __restrict__ bbase,
                                             float* __restrict__ dis, int n) {
  __shared__ float ldeg[BN];
  int b = blockIdx.x;
  int tid = threadIdx.x;
  int base = bbase[b];
  int cnt = bbase[b + 1] - base;
  for (int i = tid; i < BN; i += 256) ldeg[i] = 0.f;
  __syncthreads();
  for (int i = tid; i < cnt; i += 256) {
    uint2 r = part[base + i];
    atomicAdd(&ldeg[r.x >> 24], __uint_as_float(r.y));
  }
  __syncthreads();
  for (int t = tid; t < BN; t += 256) dis[b * BN + t] = rsqrtf(1.0f + ldeg[t]);
}

// ---------------- pass C2: per-bucket counting sort -> 4B csr (rows padded to 4) ----------------
// record = {src:16 | bf16(dis[src]*ew):16}; rows 4-aligned; gaps zero-filled (w=0).

__global__ __launch_bounds__(256) void k_bsort(const uint2* __restrict__ part, const int* __restrict__ bbase,
                                               const float* __restrict__ dis, unsigned* __restrict__ csr4,
                                               int* __restrict__ rowptr, int n, int Etot) {
  __shared__ uint2 stage[CAP];
  __shared__ int lh[BN];
  __shared__ int s[256];
  int b = blockIdx.x;
  int tid = threadIdx.x;
  int base = bbase[b];
  int cnt = bbase[b + 1] - base;
  int R  = ((base + 3) & ~3) + b * PADB;
  int Rn = ((bbase[b + 1] + 3) & ~3) + (b + 1) * PADB;
  for (int i = tid; i < BN; i += 256) lh[i] = 0;
  __syncthreads();
  for (int i = tid; i < cnt; i += 256) {
    uint2 r = part[base + i];
    if (i < CAP) stage[i] = r;
    atomicAdd(&lh[r.x >> 24], 1);
  }
  __syncthreads();
  int c = (tid < BN) ? lh[tid] : 0;
  int pc = (c + 3) & ~3;  // padded row length
  s[tid] = pc;
  __syncthreads();
#pragma unroll
  for (int off = 1; off < 256; off <<= 1) {
    int u = (tid >= off) ? s[tid - off] : 0;
    __syncthreads();
    s[tid] += u;
    __syncthreads();
  }
  int ex = s[tid] - pc;  // padded exclusive offset within bucket
  if (tid < BN) {
    lh[tid] = ex;  // becomes running cursor
    rowptr[b * BN + tid] = R + ex;
  }
  if (b == 0 && tid == 0) rowptr[n] = ((Etot + 3) & ~3) + NB * PADB;
  __syncthreads();
  // zero-fill the whole bucket region (pads become {src=0, w=0} records)
  int len = Rn - R;
  for (int i = tid; i < len; i += 256) csr4[R + i] = 0u;
  __syncthreads();
  for (int i = tid; i < cnt; i += 256) {
    uint2 r = (i < CAP) ? stage[i] : part[base + i];
    int dlow = r.x >> 24;
    unsigned srcv = r.x & 0x00FFFFFFu;
    float w = __uint_as_float(r.y) * dis[srcv];
    int p = atomicAdd(&lh[dlow], 1);
    csr4[R + p] = srcv | (bf16r(w) << 16);
  }
}

// ---------------- per-layer: GEMM via MFMA bf16 (layers 1,2) ----------------

__global__ __launch_bounds__(256) void k_gemm(const unsigned short* __restrict__ Zb,
                                              const unsigned short* __restrict__ Wt,
                                              unsigned short* __restrict__ H, int n) {
  int lane = threadIdx.x & 63;
  int wid  = threadIdx.x >> 6;
  int row0 = blockIdx.x * 16;
  int r  = lane & 15;
  int kg = lane >> 4;
  int c0 = wid * 32;
  const size_t abase  = (size_t)(row0 + r) * 128 + kg * 8;
  const size_t b0base = (size_t)(c0 + r) * 128 + kg * 8;
  const size_t b1base = (size_t)(c0 + 16 + r) * 128 + kg * 8;
  f32x4 acc0 = {0.f, 0.f, 0.f, 0.f};
  f32x4 acc1 = {0.f, 0.f, 0.f, 0.f};
#pragma unroll
  for (int k0 = 0; k0 < 128; k0 += 32) {
    bf16x8 a  = *(const bf16x8*)&Zb[abase + k0];
    bf16x8 b0 = *(const bf16x8*)&Wt[b0base + k0];
    bf16x8 b1 = *(const bf16x8*)&Wt[b1base + k0];
    acc0 = __builtin_amdgcn_mfma_f32_16x16x32_bf16(a, b0, acc0, 0, 0, 0);
    acc1 = __builtin_amdgcn_mfma_f32_16x16x32_bf16(a, b1, acc1, 0, 0, 0);
  }
  int orow = row0 + kg * 4;
#pragma unroll
  for (int j = 0; j < 4; ++j) {
    H[(size_t)(orow + j) * 128 + c0 + r]      = (unsigned short)bf16r(acc0[j]);
    H[(size_t)(orow + j) * 128 + c0 + 16 + r] = (unsigned short)bf16r(acc1[j]);
  }
}

// ---------------- per-layer: aggregation + bias + relu ----------------
// one 64-lane wave per node; 4B records (dis[src]*ew pre-folded as bf16),
// rows padded to 4 (no tail); PER-LANE broadcast record loads (keeps VGPR
// pressure + MLP — the R12 scalar-path variant serialized the gathers);
// dual accumulators break the fma chain.

__global__ __launch_bounds__(256) void k_agg(const unsigned* __restrict__ Hb, const int* __restrict__ rowptr,
                                             const unsigned* __restrict__ csr4, const float* __restrict__ dis,
                                             const float* __restrict__ bias, unsigned* __restrict__ outb,
                                             float* __restrict__ outf, int n) {
  int node = __builtin_amdgcn_readfirstlane(blockIdx.x * 4 + (threadIdx.x >> 6));
  if (node >= n) return;
  int lane = threadIdx.x & 63;
  float ax0 = 0.f, ay0 = 0.f, ax1 = 0.f, ay1 = 0.f;
  int e = rowptr[node];
  const int end = rowptr[node + 1];
  for (; e < end; e += 4) {
    unsigned r0 = __builtin_nontemporal_load(&csr4[e]);
    unsigned r1 = __builtin_nontemporal_load(&csr4[e + 1]);
    unsigned r2 = __builtin_nontemporal_load(&csr4[e + 2]);
    unsigned r3 = __builtin_nontemporal_load(&csr4[e + 3]);
    unsigned s0 = r0 & 0xFFFFu; float w0 = __uint_as_float(r0 & 0xFFFF0000u);
    unsigned s1 = r1 & 0xFFFFu; float w1 = __uint_as_float(r1 & 0xFFFF0000u);
    unsigned s2 = r2 & 0xFFFFu; float w2 = __uint_as_float(r2 & 0xFFFF0000u);
    unsigned s3 = r3 & 0xFFFFu; float w3 = __uint_as_float(r3 & 0xFFFF0000u);
    unsigned g0 = Hb[(size_t)s0 * 64 + lane];
    unsigned g1 = Hb[(size_t)s1 * 64 + lane];
    unsigned g2 = Hb[(size_t)s2 * 64 + lane];
    unsigned g3 = Hb[(size_t)s3 * 64 + lane];
    ax0 = fmaf(__uint_as_float(g0 << 16), w0, ax0); ay0 = fmaf(__uint_as_float(g0 & 0xffff0000u), w0, ay0);
    ax1 = fmaf(__uint_as_float(g1 << 16), w1, ax1); ay1 = fmaf(__uint_as_float(g1 & 0xffff0000u), w1, ay1);
    ax0 = fmaf(__uint_as_float(g2 << 16), w2, ax0); ay0 = fmaf(__uint_as_float(g2 & 0xffff0000u), w2, ay0);
    ax1 = fmaf(__uint_as_float(g3 << 16), w3, ax1); ay1 = fmaf(__uint_as_float(g3 & 0xffff0000u), w3, ay1);
  }
  float ax = ax0 + ax1, ay = ay0 + ay1;
  float dn = dis[node];
  float sn = dn * dn;
  unsigned hv = Hb[(size_t)node * 64 + lane];
  float hvx = __uint_as_float(hv << 16);
  float hvy = __uint_as_float(hv & 0xffff0000u);
  float2 bv = ((const float2*)bias)[lane];
  float ox = fmaxf(fmaf(dn, ax, fmaf(sn, hvx, bv.x)), 0.f);
  float oy = fmaxf(fmaf(dn, ay, fmaf(sn, hvy, bv.y)), 0.f);
  if (outb) {
    outb[(size_t)node * 64 + lane] = bf16r(ox) | (bf16r(oy) << 16);
  } else {
    f2v o; o.x = ox; o.y = oy;
    __builtin_nontemporal_store(o, (f2v*)outf + (size_t)node * 64 + lane);
  }
}

// ---------------- host ----------------

extern "C" void kernel_launch(void* const* d_in, const int* in_sizes, int n_in,
                              void* d_out, int out_size, void* d_ws, size_t ws_size,
                              hipStream_t stream) {
  const float* x  = (const float*)d_in[0];
  const int*   ei = (const int*)d_in[1];   // int32: [2, E] row-major
  const float* ew = (const float*)d_in[2];
  const float* W0 = (const float*)d_in[3];
  const float* W1 = (const float*)d_in[5];
  const float* W2 = (const float*)d_in[7];
  const float* bl[3] = {(const float*)d_in[4], (const float*)d_in[6], (const float*)d_in[8]};

  const int n = in_sizes[0] / D;   // 50000 == NB*BN
  const int E = in_sizes[1] / 2;
  const int* src = ei;
  const int* dst = ei + E;

  char* p = (char*)d_ws;
  unsigned short* Zb     = (unsigned short*)p; p += (size_t)n * D * 2;  // xb for layer 0
  unsigned short* H      = (unsigned short*)p; p += (size_t)n * D * 2;
  float*          dis    = (float*)p;          p += (size_t)n * 4;
  int*            rowptr = (int*)p;            p += (size_t)(n + 1) * 4;
  int*            M      = (int*)p;            p += (size_t)NB * NBLK * 4;
  int*            bbase  = (int*)p;            p += (size_t)(NB + 1) * 4;
  int*            bsum2  = (int*)p;            p += 512 * 4;
  int*            boff2  = (int*)p;            p += 512 * 4;
  uint2*          part   = (uint2*)p;          p += (size_t)E * 8;
  unsigned*       csr4   = (unsigned*)p;       p += ((size_t)E + NB * PADB + 64) * 4;
  unsigned short* Wt     = (unsigned short*)p; p += 3 * 16384 * 2;
  (void)ws_size; (void)n_in;

  const int total4 = n * D / 4;            // 1.6M
  const int GC = (total4 + 255) / 256;     // 6250
  const int GW = (3 * 16384 + 255) / 256;  // 192
  const int GG = n / 16;                   // 3125 (n % 16 == 0)
  const int flatN = NB * NBLK;             // 128000
  const int GS = flatN / 256;              // 500

  k_pre1<<<NBLK + GC + GW, 256, 0, stream>>>(dst, M, E, x, Zb, total4, GC, W0, W1, W2, Wt);
  k_blocksum<<<GS, 256, 0, stream>>>(M, bsum2, flatN);
  k_scanb2<<<1, 512, 0, stream>>>(bsum2, boff2, GS);
  k_scanm<<<GS, 256, 0, stream>>>(M, boff2, bbase, flatN, E);
  k_pre2<<<GG + NBLK, 256, 0, stream>>>(Zb, Wt, H, n, GG, src, dst, ew, M, part, E);
  k_deg<<<NB, 256, 0, stream>>>(part, bbase, dis, n);
  k_bsort<<<NB, 256, 0, stream>>>(part, bbase, dis, csr4, rowptr, n, E);

  float* outp = (float*)d_out;
  // layer 0 aggregation (gemm0 already done inside k_pre2)
  k_agg<<<(n + 3) / 4, 256, 0, stream>>>((const unsigned*)H, rowptr, csr4, dis, bl[0], (unsigned*)Zb, outp, n);
  for (int l = 1; l < 3; ++l) {
    k_gemm<<<GG, 256, 0, stream>>>(Zb, Wt + l * 16384, H, n);
    unsigned* ob = (l == 2) ? nullptr : (unsigned*)Zb;
    k_agg<<<(n + 3) / 4, 256, 0, stream>>>((const unsigned*)H, rowptr, csr4, dis, bl[l], ob, outp, n);
  }
}

// Round 14
// 203.801 us; speedup vs baseline: 1.2019x; 1.2019x over previous
//
#include <hip/hip_runtime.h>

#define D 128
#define NB 250    // node buckets
#define BN 200    // nodes per bucket (NB*BN == n == 50000)
#define NBLK 512  // histogram/partition blocks (power of 2)
#define CAP 7168  // LDS-staged edges per bucket; global-read fallback past this

typedef float f2v __attribute__((ext_vector_type(2)));
typedef short bf16x8 __attribute__((ext_vector_type(8)));
typedef float f32x4 __attribute__((ext_vector_type(4)));

// bf16 round-to-nearest-even
__device__ __forceinline__ unsigned bf16r(float f) {
  unsigned u = __float_as_uint(f);
  return (u + 0x7fffu + ((u >> 16) & 1u)) >> 16;
}

// ---------------- pass A + converts ----------------
// blocks [0,NBLK): LDS bucket histogram of dst -> M[bkt][blk] (transposed)
// blocks [NBLK,NBLK+GC): x -> bf16 ; rest: W -> bf16 transposed [n][k]

__global__ __launch_bounds__(256) void k_pre1(const int* __restrict__ dst, int* __restrict__ M, int E,
                                              const float* __restrict__ X, unsigned short* __restrict__ Xb,
                                              int total4, int GC,
                                              const float* __restrict__ W0, const float* __restrict__ W1,
                                              const float* __restrict__ W2, unsigned short* __restrict__ Wt) {
  __shared__ int lh[NB];
  int b = blockIdx.x;
  int tid = threadIdx.x;
  if (b < NBLK) {
    for (int i = tid; i < NB; i += 256) lh[i] = 0;
    __syncthreads();
    const int EPB = (E + NBLK - 1) / NBLK;
    int e0 = b * EPB;
    int e1 = min(e0 + EPB, E);
    for (int e = e0 + tid; e < e1; e += 256) atomicAdd(&lh[dst[e] / BN], 1);
    __syncthreads();
    for (int i = tid; i < NB; i += 256) M[i * NBLK + b] = lh[i];
  } else if (b < NBLK + GC) {
    int i = (b - NBLK) * 256 + tid;
    if (i < total4) {
      float4 v = ((const float4*)X)[i];
      ushort4 o;
      o.x = (unsigned short)bf16r(v.x);
      o.y = (unsigned short)bf16r(v.y);
      o.z = (unsigned short)bf16r(v.z);
      o.w = (unsigned short)bf16r(v.w);
      ((ushort4*)Xb)[i] = o;
    }
  } else {
    int i = (b - NBLK - GC) * 256 + tid;
    if (i < 3 * 16384) {
      int l = i >> 14;
      int r = i & 16383;
      int nn = r >> 7, kk = r & 127;
      const float* W = (l == 0) ? W0 : (l == 1) ? W1 : W2;
      Wt[i] = (unsigned short)bf16r(W[kk * 128 + nn]);
    }
  }
}

// ---------------- hierarchical scan of M (flat, bucket-major) ----------------

__global__ __launch_bounds__(256) void k_blocksum(const int* __restrict__ cnt, int* __restrict__ bsum, int n) {
  int i = blockIdx.x * 256 + threadIdx.x;
  int v = (i < n) ? cnt[i] : 0;
#pragma unroll
  for (int off = 32; off > 0; off >>= 1) v += __shfl_down(v, off);
  __shared__ int ws[4];
  if ((threadIdx.x & 63) == 0) ws[threadIdx.x >> 6] = v;
  __syncthreads();
  if (threadIdx.x == 0) bsum[blockIdx.x] = ws[0] + ws[1] + ws[2] + ws[3];
}

__global__ __launch_bounds__(512) void k_scanb2(const int* __restrict__ bsum, int* __restrict__ boff, int nb) {
  __shared__ int s[512];
  int t = threadIdx.x;
  int v = (t < nb) ? bsum[t] : 0;
  s[t] = v;
  __syncthreads();
#pragma unroll
  for (int off = 1; off < 512; off <<= 1) {
    int u = (t >= off) ? s[t - off] : 0;
    __syncthreads();
    s[t] += u;
    __syncthreads();
  }
  if (t < nb) boff[t] = s[t] - v;  // exclusive
}

__global__ __launch_bounds__(256) void k_scanm(int* __restrict__ M, const int* __restrict__ boff,
                                               int* __restrict__ bbase, int flatN, int Etot) {
  __shared__ int s[256];
  int t = threadIdx.x;
  int i = blockIdx.x * 256 + t;
  int v = (i < flatN) ? M[i] : 0;
  s[t] = v;
  __syncthreads();
#pragma unroll
  for (int off = 1; off < 256; off <<= 1) {
    int u = (t >= off) ? s[t - off] : 0;
    __syncthreads();
    s[t] += u;
    __syncthreads();
  }
  int ex = s[t] - v + boff[blockIdx.x];
  if (i < flatN) {
    M[i] = ex;
    if ((i & (NBLK - 1)) == 0) bbase[i / NBLK] = ex;
  }
  if (i == 0) bbase[NB] = Etot;
}

// ---------------- pass B + layer-0 GEMM ----------------

__global__ __launch_bounds__(256) void k_pre2(const unsigned short* __restrict__ Zb,
                                              const unsigned short* __restrict__ Wt,
                                              unsigned short* __restrict__ H, int n, int GG,
                                              const int* __restrict__ src, const int* __restrict__ dst,
                                              const float* __restrict__ ew, const int* __restrict__ M,
                                              uint2* __restrict__ part, int E) {
  __shared__ int lcur[NB];
  int b = blockIdx.x;
  if (b < GG) {
    int lane = threadIdx.x & 63;
    int wid  = threadIdx.x >> 6;
    int row0 = b * 16;
    int r  = lane & 15;
    int kg = lane >> 4;
    int c0 = wid * 32;
    const size_t abase  = (size_t)(row0 + r) * 128 + kg * 8;
    const size_t b0base = (size_t)(c0 + r) * 128 + kg * 8;
    const size_t b1base = (size_t)(c0 + 16 + r) * 128 + kg * 8;
    f32x4 acc0 = {0.f, 0.f, 0.f, 0.f};
    f32x4 acc1 = {0.f, 0.f, 0.f, 0.f};
#pragma unroll
    for (int k0 = 0; k0 < 128; k0 += 32) {
      bf16x8 a  = *(const bf16x8*)&Zb[abase + k0];
      bf16x8 b0 = *(const bf16x8*)&Wt[b0base + k0];
      bf16x8 b1 = *(const bf16x8*)&Wt[b1base + k0];
      acc0 = __builtin_amdgcn_mfma_f32_16x16x32_bf16(a, b0, acc0, 0, 0, 0);
      acc1 = __builtin_amdgcn_mfma_f32_16x16x32_bf16(a, b1, acc1, 0, 0, 0);
    }
    int orow = row0 + kg * 4;
#pragma unroll
    for (int j = 0; j < 4; ++j) {
      H[(size_t)(orow + j) * 128 + c0 + r]      = (unsigned short)bf16r(acc0[j]);
      H[(size_t)(orow + j) * 128 + c0 + 16 + r] = (unsigned short)bf16r(acc1[j]);
    }
  } else {
    int blk = b - GG;
    int tid = threadIdx.x;
    for (int i = tid; i < NB; i += 256) lcur[i] = M[i * NBLK + blk];
    __syncthreads();
    const int EPB = (E + NBLK - 1) / NBLK;
    int e0 = blk * EPB;
    int e1 = min(e0 + EPB, E);
    for (int e = e0 + tid; e < e1; e += 256) {
      int d = dst[e];
      int bkt = d / BN;
      int dlow = d - bkt * BN;
      int p = atomicAdd(&lcur[bkt], 1);
      uint2 rec;
      rec.x = (unsigned)src[e] | ((unsigned)dlow << 24);
      rec.y = __float_as_uint(ew[e]);
      part[p] = rec;
    }
  }
}

// ---------------- pass C: per-bucket counting sort -> csr, rowptr, dis ----------------
// (R11 form: single pass, 8B records {src24, ew}, no padding)

__global__ __launch_bounds__(256) void k_bsort(const uint2* __restrict__ part, const int* __restrict__ bbase,
                                               uint2* __restrict__ csr, int* __restrict__ rowptr,
                                               float* __restrict__ dis, int n, int E) {
  __shared__ uint2 stage[CAP];
  __shared__ int lh[BN];
  __shared__ float ldeg[BN];
  __shared__ int s[256];
  int b = blockIdx.x;
  int tid = threadIdx.x;
  int base = bbase[b];
  int cnt = bbase[b + 1] - base;
  for (int i = tid; i < BN; i += 256) { lh[i] = 0; ldeg[i] = 0.f; }
  __syncthreads();
  for (int i = tid; i < cnt; i += 256) {
    uint2 r = part[base + i];
    if (i < CAP) stage[i] = r;
    int dlow = r.x >> 24;
    atomicAdd(&lh[dlow], 1);
    atomicAdd(&ldeg[dlow], __uint_as_float(r.y));
  }
  __syncthreads();
  int v = (tid < BN) ? lh[tid] : 0;
  s[tid] = v;
  __syncthreads();
#pragma unroll
  for (int off = 1; off < 256; off <<= 1) {
    int u = (tid >= off) ? s[tid - off] : 0;
    __syncthreads();
    s[tid] += u;
    __syncthreads();
  }
  int ex = s[tid] - v;  // exclusive node offset within bucket
  if (tid < BN) {
    lh[tid] = ex;  // becomes running cursor
    int node = b * BN + tid;
    rowptr[node] = base + ex;
    dis[node] = rsqrtf(1.0f + ldeg[tid]);
  }
  if (b == 0 && tid == 0) rowptr[n] = E;
  __syncthreads();
  for (int i = tid; i < cnt; i += 256) {
    uint2 r = (i < CAP) ? stage[i] : part[base + i];
    int dlow = r.x >> 24;
    int p = atomicAdd(&lh[dlow], 1);
    uint2 o;
    o.x = r.x & 0x00FFFFFFu;
    o.y = r.y;
    csr[base + p] = o;
  }
}

// ---------------- per-layer: GEMM via MFMA bf16 (layers 1,2) ----------------

__global__ __launch_bounds__(256) void k_gemm(const unsigned short* __restrict__ Zb,
                                              const unsigned short* __restrict__ Wt,
                                              unsigned short* __restrict__ H, int n) {
  int lane = threadIdx.x & 63;
  int wid  = threadIdx.x >> 6;
  int row0 = blockIdx.x * 16;
  int r  = lane & 15;
  int kg = lane >> 4;
  int c0 = wid * 32;
  const size_t abase  = (size_t)(row0 + r) * 128 + kg * 8;
  const size_t b0base = (size_t)(c0 + r) * 128 + kg * 8;
  const size_t b1base = (size_t)(c0 + 16 + r) * 128 + kg * 8;
  f32x4 acc0 = {0.f, 0.f, 0.f, 0.f};
  f32x4 acc1 = {0.f, 0.f, 0.f, 0.f};
#pragma unroll
  for (int k0 = 0; k0 < 128; k0 += 32) {
    bf16x8 a  = *(const bf16x8*)&Zb[abase + k0];
    bf16x8 b0 = *(const bf16x8*)&Wt[b0base + k0];
    bf16x8 b1 = *(const bf16x8*)&Wt[b1base + k0];
    acc0 = __builtin_amdgcn_mfma_f32_16x16x32_bf16(a, b0, acc0, 0, 0, 0);
    acc1 = __builtin_amdgcn_mfma_f32_16x16x32_bf16(a, b1, acc1, 0, 0, 0);
  }
  int orow = row0 + kg * 4;
#pragma unroll
  for (int j = 0; j < 4; ++j) {
    H[(size_t)(orow + j) * 128 + c0 + r]      = (unsigned short)bf16r(acc0[j]);
    H[(size_t)(orow + j) * 128 + c0 + 16 + r] = (unsigned short)bf16r(acc1[j]);
  }
}

// ---------------- per-layer: aggregation + bias + relu ----------------
// R11 structure (8B nt records, in-kernel dis[src]) + 8-edge unroll and
// dual accumulator chains for more outstanding gathers per wave.

__global__ __launch_bounds__(256) void k_agg(const unsigned* __restrict__ Hb, const int* __restrict__ rowptr,
                                             const f2v* __restrict__ csr, const float* __restrict__ dis,
                                             const float* __restrict__ bias, unsigned* __restrict__ outb,
                                             float* __restrict__ outf, int n) {
  int node = __builtin_amdgcn_readfirstlane(blockIdx.x * 4 + (threadIdx.x >> 6));
  if (node >= n) return;
  int lane = threadIdx.x & 63;
  float ax0 = 0.f, ay0 = 0.f, ax1 = 0.f, ay1 = 0.f;
  int e = rowptr[node];
  const int end = rowptr[node + 1];
  for (; e + 8 <= end; e += 8) {
    f2v r0 = __builtin_nontemporal_load(&csr[e]);
    f2v r1 = __builtin_nontemporal_load(&csr[e + 1]);
    f2v r2 = __builtin_nontemporal_load(&csr[e + 2]);
    f2v r3 = __builtin_nontemporal_load(&csr[e + 3]);
    f2v r4 = __builtin_nontemporal_load(&csr[e + 4]);
    f2v r5 = __builtin_nontemporal_load(&csr[e + 5]);
    f2v r6 = __builtin_nontemporal_load(&csr[e + 6]);
    f2v r7 = __builtin_nontemporal_load(&csr[e + 7]);
    int s0 = __float_as_int(r0.x), s1 = __float_as_int(r1.x);
    int s2 = __float_as_int(r2.x), s3 = __float_as_int(r3.x);
    int s4 = __float_as_int(r4.x), s5 = __float_as_int(r5.x);
    int s6 = __float_as_int(r6.x), s7 = __float_as_int(r7.x);
    unsigned g0 = Hb[(size_t)s0 * 64 + lane];
    unsigned g1 = Hb[(size_t)s1 * 64 + lane];
    unsigned g2 = Hb[(size_t)s2 * 64 + lane];
    unsigned g3 = Hb[(size_t)s3 * 64 + lane];
    unsigned g4 = Hb[(size_t)s4 * 64 + lane];
    unsigned g5 = Hb[(size_t)s5 * 64 + lane];
    unsigned g6 = Hb[(size_t)s6 * 64 + lane];
    unsigned g7 = Hb[(size_t)s7 * 64 + lane];
    float w0 = r0.y * dis[s0];
    float w1 = r1.y * dis[s1];
    float w2 = r2.y * dis[s2];
    float w3 = r3.y * dis[s3];
    float w4 = r4.y * dis[s4];
    float w5 = r5.y * dis[s5];
    float w6 = r6.y * dis[s6];
    float w7 = r7.y * dis[s7];
    ax0 = fmaf(__uint_as_float(g0 << 16), w0, ax0); ay0 = fmaf(__uint_as_float(g0 & 0xffff0000u), w0, ay0);
    ax1 = fmaf(__uint_as_float(g1 << 16), w1, ax1); ay1 = fmaf(__uint_as_float(g1 & 0xffff0000u), w1, ay1);
    ax0 = fmaf(__uint_as_float(g2 << 16), w2, ax0); ay0 = fmaf(__uint_as_float(g2 & 0xffff0000u), w2, ay0);
    ax1 = fmaf(__uint_as_float(g3 << 16), w3, ax1); ay1 = fmaf(__uint_as_float(g3 & 0xffff0000u), w3, ay1);
    ax0 = fmaf(__uint_as_float(g4 << 16), w4, ax0); ay0 = fmaf(__uint_as_float(g4 & 0xffff0000u), w4, ay0);
    ax1 = fmaf(__uint_as_float(g5 << 16), w5, ax1); ay1 = fmaf(__uint_as_float(g5 & 0xffff0000u), w5, ay1);
    ax0 = fmaf(__uint_as_float(g6 << 16), w6, ax0); ay0 = fmaf(__uint_as_float(g6 & 0xffff0000u), w6, ay0);
    ax1 = fmaf(__uint_as_float(g7 << 16), w7, ax1); ay1 = fmaf(__uint_as_float(g7 & 0xffff0000u), w7, ay1);
  }
  for (; e + 4 <= end; e += 4) {
    f2v r0 = __builtin_nontemporal_load(&csr[e]);
    f2v r1 = __builtin_nontemporal_load(&csr[e + 1]);
    f2v r2 = __builtin_nontemporal_load(&csr[e + 2]);
    f2v r3 = __builtin_nontemporal_load(&csr[e + 3]);
    int s0 = __float_as_int(r0.x), s1 = __float_as_int(r1.x);
    int s2 = __float_as_int(r2.x), s3 = __float_as_int(r3.x);
    unsigned g0 = Hb[(size_t)s0 * 64 + lane];
    unsigned g1 = Hb[(size_t)s1 * 64 + lane];
    unsigned g2 = Hb[(size_t)s2 * 64 + lane];
    unsigned g3 = Hb[(size_t)s3 * 64 + lane];
    float w0 = r0.y * dis[s0];
    float w1 = r1.y * dis[s1];
    float w2 = r2.y * dis[s2];
    float w3 = r3.y * dis[s3];
    ax0 = fmaf(__uint_as_float(g0 << 16), w0, ax0); ay0 = fmaf(__uint_as_float(g0 & 0xffff0000u), w0, ay0);
    ax1 = fmaf(__uint_as_float(g1 << 16), w1, ax1); ay1 = fmaf(__uint_as_float(g1 & 0xffff0000u), w1, ay1);
    ax0 = fmaf(__uint_as_float(g2 << 16), w2, ax0); ay0 = fmaf(__uint_as_float(g2 & 0xffff0000u), w2, ay0);
    ax1 = fmaf(__uint_as_float(g3 << 16), w3, ax1); ay1 = fmaf(__uint_as_float(g3 & 0xffff0000u), w3, ay1);
  }
  for (; e < end; ++e) {
    f2v r0 = __builtin_nontemporal_load(&csr[e]);
    int s0 = __float_as_int(r0.x);
    unsigned g0 = Hb[(size_t)s0 * 64 + lane];
    float w0 = r0.y * dis[s0];
    ax0 = fmaf(__uint_as_float(g0 << 16), w0, ax0); ay0 = fmaf(__uint_as_float(g0 & 0xffff0000u), w0, ay0);
  }
  float ax = ax0 + ax1, ay = ay0 + ay1;
  float dn = dis[node];
  float sn = dn * dn;
  unsigned hv = Hb[(size_t)node * 64 + lane];
  float hvx = __uint_as_float(hv << 16);
  float hvy = __uint_as_float(hv & 0xffff0000u);
  float2 bv = ((const float2*)bias)[lane];
  float ox = fmaxf(fmaf(dn, ax, fmaf(sn, hvx, bv.x)), 0.f);
  float oy = fmaxf(fmaf(dn, ay, fmaf(sn, hvy, bv.y)), 0.f);
  if (outb) {
    outb[(size_t)node * 64 + lane] = bf16r(ox) | (bf16r(oy) << 16);
  } else {
    f2v o; o.x = ox; o.y = oy;
    __builtin_nontemporal_store(o, (f2v*)outf + (size_t)node * 64 + lane);
  }
}

// ---------------- host ----------------

extern "C" void kernel_launch(void* const* d_in, const int* in_sizes, int n_in,
                              void* d_out, int out_size, void* d_ws, size_t ws_size,
                              hipStream_t stream) {
  const float* x  = (const float*)d_in[0];
  const int*   ei = (const int*)d_in[1];   // int32: [2, E] row-major
  const float* ew = (const float*)d_in[2];
  const float* W0 = (const float*)d_in[3];
  const float* W1 = (const float*)d_in[5];
  const float* W2 = (const float*)d_in[7];
  const float* bl[3] = {(const float*)d_in[4], (const float*)d_in[6], (const float*)d_in[8]};

  const int n = in_sizes[0] / D;   // 50000 == NB*BN
  const int E = in_sizes[1] / 2;
  const int* src = ei;
  const int* dst = ei + E;

  char* p = (char*)d_ws;
  unsigned short* Zb     = (unsigned short*)p; p += (size_t)n * D * 2;  // xb for layer 0
  unsigned short* H      = (unsigned short*)p; p += (size_t)n * D * 2;
  float*          dis    = (float*)p;          p += (size_t)n * 4;
  int*            rowptr = (int*)p;            p += (size_t)(n + 1) * 4;
  int*            M      = (int*)p;            p += (size_t)NB * NBLK * 4;
  int*            bbase  = (int*)p;            p += (size_t)(NB + 1) * 4;
  int*            bsum2  = (int*)p;            p += 512 * 4;
  int*            boff2  = (int*)p;            p += 512 * 4;
  uint2*          part   = (uint2*)p;          p += (size_t)E * 8;
  uint2*          csr    = (uint2*)p;          p += (size_t)E * 8;
  unsigned short* Wt     = (unsigned short*)p; p += 3 * 16384 * 2;
  (void)ws_size; (void)n_in;

  const int total4 = n * D / 4;            // 1.6M
  const int GC = (total4 + 255) / 256;     // 6250
  const int GW = (3 * 16384 + 255) / 256;  // 192
  const int GG = n / 16;                   // 3125 (n % 16 == 0)
  const int flatN = NB * NBLK;             // 128000
  const int GS = flatN / 256;              // 500

  k_pre1<<<NBLK + GC + GW, 256, 0, stream>>>(dst, M, E, x, Zb, total4, GC, W0, W1, W2, Wt);
  k_blocksum<<<GS, 256, 0, stream>>>(M, bsum2, flatN);
  k_scanb2<<<1, 512, 0, stream>>>(bsum2, boff2, GS);
  k_scanm<<<GS, 256, 0, stream>>>(M, boff2, bbase, flatN, E);
  k_pre2<<<GG + NBLK, 256, 0, stream>>>(Zb, Wt, H, n, GG, src, dst, ew, M, part, E);
  k_bsort<<<NB, 256, 0, stream>>>(part, bbase, csr, rowptr, dis, n, E);

  float* outp = (float*)d_out;
  // layer 0 aggregation (gemm0 already done inside k_pre2)
  k_agg<<<(n + 3) / 4, 256, 0, stream>>>((const unsigned*)H, rowptr, (const f2v*)csr, dis, bl[0], (unsigned*)Zb, outp, n);
  for (int l = 1; l < 3; ++l) {
    k_gemm<<<GG, 256, 0, stream>>>(Zb, Wt + l * 16384, H, n);
    unsigned* ob = (l == 2) ? nullptr : (unsigned*)Zb;
    k_agg<<<(n + 3) / 4, 256, 0, stream>>>((const unsigned*)H, rowptr, (const f2v*)csr, dis, bl[l], ob, outp, n);
  }
}